// Round 14
// baseline (491.916 us; speedup 1.0000x reference)
//
#include <hip/hip_runtime.h>
#include <cmath>

#define H 128
#define EPS 1e-5f

typedef __attribute__((ext_vector_type(8))) __bf16 bf16x8;
typedef __attribute__((ext_vector_type(4))) float f32x4;
typedef __attribute__((ext_vector_type(2))) float f32x2;
typedef __attribute__((ext_vector_type(4))) unsigned short u16x4;
typedef __attribute__((ext_vector_type(8))) unsigned short u16x8;
typedef __attribute__((ext_vector_type(4))) int i32x4;

// Fast GELU (sigmoid form); verified R9: absmax unchanged vs erff.
__device__ __forceinline__ float gelu_fast(float x) {
    float t2 = -1.5957691216057308f * fmaf(0.044715f * x * x, x, x); // -2t
    return x * __builtin_amdgcn_rcpf(1.0f + __expf(t2));
}

__device__ __forceinline__ unsigned short f2bfu(float f) {
    __bf16 h = (__bf16)f;   // RNE fptrunc
    return __builtin_bit_cast(unsigned short, h);
}

__device__ __forceinline__ float bfu2f(unsigned short u) {
    return __builtin_bit_cast(float, (unsigned)u << 16);
}

// async global -> LDS, 16B per lane (lane i lands at ldsbase + i*16).
__device__ __forceinline__ void gld16(const void* g, void* l) {
    __builtin_amdgcn_global_load_lds(
        (__attribute__((address_space(1))) void*)(g),
        (__attribute__((address_space(3))) void*)(l), 16, 0, 0);
}

// ---------------------------------------------------------------------------
// Zero scratch (in-graph hipMemsetAsync measured 195us for 324 KB in R7).
// ---------------------------------------------------------------------------
__global__ __launch_bounds__(256) void zero_kernel(int* __restrict__ p, int n4)
{
    int i = blockIdx.x * blockDim.x + threadIdx.x;
    const int stride = gridDim.x * blockDim.x;
    i32x4 z = {0, 0, 0, 0};
    for (; i < n4; i += stride)
        reinterpret_cast<i32x4*>(p)[i] = z;
}

// ---------------------------------------------------------------------------
// x -> bf16 (halves x gather traffic; L2/L3-resident source for fragments).
// ---------------------------------------------------------------------------
__global__ __launch_bounds__(256) void convert_x(const float* __restrict__ x,
                                                 unsigned short* __restrict__ xb,
                                                 long n8)
{
    long i = (long)blockIdx.x * blockDim.x + threadIdx.x;
    const long stride = (long)gridDim.x * blockDim.x;
    for (; i < n8; i += stride) {
        f32x4 a = *reinterpret_cast<const f32x4*>(x + i * 8);
        f32x4 b = *reinterpret_cast<const f32x4*>(x + i * 8 + 4);
        u16x8 o;
#pragma unroll
        for (int j = 0; j < 4; ++j) { o[j] = f2bfu(a[j]); o[j + 4] = f2bfu(b[j]); }
        *reinterpret_cast<u16x8*>(xb + i * 8) = o;
    }
}

// ---------------------------------------------------------------------------
// Counting sort of edges by dst -> perm, dsts, offs. Multi-block scan.
// ---------------------------------------------------------------------------
__global__ __launch_bounds__(256) void hist_kernel(const int* __restrict__ dst,
                                                   int* __restrict__ cnt, int E)
{
    int i = blockIdx.x * blockDim.x + threadIdx.x;
    const int stride = gridDim.x * blockDim.x;
    for (; i < E; i += stride) atomicAdd(&cnt[dst[i]], 1);
}

__global__ __launch_bounds__(256) void scan_p1(const int* __restrict__ cnt,
                                               int* __restrict__ otmp,
                                               int* __restrict__ bsum, int Nn)
{
    __shared__ int sh[256];
    const int t = threadIdx.x;
    const int idx = blockIdx.x * 256 + t;
    int v = idx < Nn ? cnt[idx] : 0;
    sh[t] = v;
    __syncthreads();
    for (int d = 1; d < 256; d <<= 1) {
        int u = (t >= d) ? sh[t - d] : 0;
        __syncthreads();
        sh[t] += u;
        __syncthreads();
    }
    if (idx < Nn) otmp[idx] = sh[t] - v;
    if (t == 255) bsum[blockIdx.x] = sh[t];
}

__global__ __launch_bounds__(256) void scan_p2(const int* __restrict__ bsum,
                                               int* __restrict__ boff, int nb,
                                               int* __restrict__ offs, int Nn, int E)
{
    __shared__ int sh[256];
    const int t = threadIdx.x;
    int v = t < nb ? bsum[t] : 0;
    sh[t] = v;
    __syncthreads();
    for (int d = 1; d < 256; d <<= 1) {
        int u = (t >= d) ? sh[t - d] : 0;
        __syncthreads();
        sh[t] += u;
        __syncthreads();
    }
    if (t < nb) boff[t] = sh[t] - v;
    if (t == 0) offs[Nn] = E;
}

__global__ __launch_bounds__(256) void scan_p3(const int* __restrict__ otmp,
                                               const int* __restrict__ boff,
                                               int* __restrict__ offs, int Nn)
{
    const int idx = blockIdx.x * 256 + threadIdx.x;
    if (idx < Nn) offs[idx] = otmp[idx] + boff[blockIdx.x];
}

__global__ __launch_bounds__(256) void scatter_perm(const int* __restrict__ dst,
                                                    const int* __restrict__ offs,
                                                    int* __restrict__ cur2,
                                                    int* __restrict__ perm,
                                                    int* __restrict__ dsts, int E)
{
    int i = blockIdx.x * blockDim.x + threadIdx.x;
    const int stride = gridDim.x * blockDim.x;
    for (; i < E; i += stride) {
        int n = dst[i];
        int p = offs[n] + atomicAdd(&cur2[n], 1);
        perm[p] = i;
        dsts[p] = n;
    }
}

// ---------------------------------------------------------------------------
// FULLY-FUSED edge phase, PERSISTENT + DOUBLE-BUFFERED async prefetch.
// Per tile: STAGE(buf^1, t+stride) [16 gld16, zero VGPR] -> COMPUTE(buf)
// -> __syncthreads() [its vmcnt(0) drains the prefetch AFTER compute] ->
// swap. Metadata (perm/dsts/src) pipelined 2 tiles ahead. x fragments read
// direct from L2-resident bf16 xbf inside compute. ea/bases staged f32 with
// pre-XOR'd source chunks (rule #21); swizzled LDS reads.
// ---------------------------------------------------------------------------
__global__ __launch_bounds__(256) void edge_aggr(
    const unsigned short* __restrict__ xbf, const float* __restrict__ ea,
    const float* __restrict__ bases, const int* __restrict__ src,
    const int* __restrict__ perm, const int* __restrict__ dsts,
    const float* __restrict__ W1, const float* __restrict__ b1,
    float* __restrict__ aggr, int E)
{
    __shared__ __align__(16) float ealds[2][64 * 128];   // 2 x 32 KB
    __shared__ __align__(16) float blds[2][64 * 128];    // 2 x 32 KB -> 128 KB

    const int tid = threadIdx.x;
    const int w = tid >> 6, l = tid & 63, lg = l >> 4, lr = l & 15;

    // W1 A-fragments: rows w*32 + ni*16 + lr, k = kk*32 + lg*8 .. +8
    bf16x8 wf[2][4];
    f32x4 b1v[2];
#pragma unroll
    for (int ni = 0; ni < 2; ++ni) {
        int row = w * 32 + ni * 16 + lr;
#pragma unroll
        for (int kk = 0; kk < 4; ++kk) {
            const float* p = W1 + row * H + kk * 32 + lg * 8;
            u16x8 tt;
#pragma unroll
            for (int i = 0; i < 8; ++i) tt[i] = f2bfu(p[i]);
            wf[ni][kk] = __builtin_bit_cast(bf16x8, tt);
        }
        b1v[ni] = *reinterpret_cast<const f32x4*>(b1 + w * 32 + ni * 16 + lg * 4);
    }

    const int ntiles = (E + 63) / 64;
    int t = blockIdx.x;
    if (t >= ntiles) return;
    const int tstride = gridDim.x;

#define LOADMETA(ELV, NDV, SRV, TT)                                          \
    {                                                                        \
        int ic_ = (TT) * 64 + l;                                             \
        ic_ = ic_ < E ? ic_ : E - 1;                                         \
        ELV = perm[ic_];                                                     \
        NDV = dsts[ic_];                                                     \
        SRV = src[ELV];                                                      \
    }

#define STAGE(BB, ELV)                                                       \
    {                                                                        \
        _Pragma("unroll")                                                    \
        for (int j = 0; j < 8; ++j) {                                        \
            const int r_ = (w << 4) + (j << 1) + (l >> 5);                   \
            const int e_ = __shfl(ELV, r_);                                  \
            const int cs_ = (l & 31) ^ (r_ & 7);                             \
            const int rb_ = (((w << 4) + (j << 1)) << 7);                    \
            gld16(ea + (long)e_ * H + cs_ * 4, &ealds[BB][rb_]);             \
            gld16(bases + (long)e_ * H + cs_ * 4, &blds[BB][rb_]);           \
        }                                                                    \
    }

    int el0, nd0, sr0, el1, nd1, sr1, el2, nd2, sr2;
    LOADMETA(el0, nd0, sr0, t);
    STAGE(0, el0);
    LOADMETA(el1, nd1, sr1, t + tstride);
    __syncthreads();          // drain buf0 (pipeline fill, once)

    int cur = 0;
    const int col0base = w * 32 + lg * 4;
    while (true) {
        const bool more = (t + tstride) < ntiles;
        if (more) STAGE(cur ^ 1, el1);               // prefetch next tile
        LOADMETA(el2, nd2, sr2, t + 2 * tstride);    // meta 2 ahead (hidden)

        const int e0 = t * 64;
#pragma unroll
        for (int s = 0; s < 4; ++s) {
            const int arow = s * 16 + lr;
            const int fswz = arow & 7;

            // x fragments direct from L2-resident bf16 x
            const long xrow = (long)__shfl(sr0, arow) * H;
            u16x8 xv[4];
#pragma unroll
            for (int kk = 0; kk < 4; ++kk)
                xv[kk] = *reinterpret_cast<const u16x8*>(xbf + xrow + kk * 32 + lg * 8);

            // posE fragments: ea (f32 LDS) + x -> bf16 pack
            bf16x8 af[4];
#pragma unroll
            for (int kk = 0; kk < 4; ++kk) {
                const int cc = kk * 8 + lg * 2;
                f32x4 elo = *reinterpret_cast<const f32x4*>(
                    &ealds[cur][arow * 128 + ((cc ^ fswz) << 2)]);
                f32x4 ehi = *reinterpret_cast<const f32x4*>(
                    &ealds[cur][arow * 128 + (((cc + 1) ^ fswz) << 2)]);
                u16x8 o;
#pragma unroll
                for (int r = 0; r < 4; ++r) {
                    o[r]     = f2bfu(elo[r] + bfu2f(xv[kk][r]));
                    o[r + 4] = f2bfu(ehi[r] + bfu2f(xv[kk][r + 4]));
                }
                af[kk] = __builtin_bit_cast(bf16x8, o);
            }

            const int es = e0 + arow;
            const bool ok = es < E;
            const int nd = __shfl(nd0, arow);
            const int ndp = __shfl(nd0, arow - 1);   // arow==0 masked by lr==0
            const bool head = ok && (lr == 0 || nd != ndp);

#pragma unroll
            for (int ni = 0; ni < 2; ++ni) {
                f32x4 a4 = b1v[ni];   // bias as C-init
#pragma unroll
                for (int kk = 0; kk < 4; ++kk)
                    a4 = __builtin_amdgcn_mfma_f32_16x16x32_bf16(wf[ni][kk], af[kk], a4, 0, 0, 0);

                const int col0 = col0base + ni * 16;
                const int bcc = col0 >> 2;
                f32x4 bq = *reinterpret_cast<const f32x4*>(
                    &blds[cur][arow * 128 + ((bcc ^ fswz) << 2)]);
                f32x4 v;
#pragma unroll
                for (int r = 0; r < 4; ++r)
                    v[r] = ok ? gelu_fast(a4[r]) * bq[r] : 0.f;

                // Kogge-Stone segmented suffix-sum across lr (16-lane groups)
#pragma unroll
                for (int d = 1; d < 16; d <<= 1) {
                    f32x4 vn;
#pragma unroll
                    for (int r = 0; r < 4; ++r) vn[r] = __shfl_down(v[r], d);
                    int ndn = __shfl_down(nd, d);
                    bool take = (lr + d < 16) && (ndn == nd);
#pragma unroll
                    for (int r = 0; r < 4; ++r) v[r] += take ? vn[r] : 0.f;
                }

                if (head) {
                    float* dstp = aggr + (long)nd * H + col0;
#pragma unroll
                    for (int r = 0; r < 4; ++r) atomicAdd(&dstp[r], v[r]);
                }
            }
        }

        if (!more) break;
        __syncthreads();      // drains prefetch (overlapped compute) + buf reuse
        el0 = el1; nd0 = nd1; sr0 = sr1;
        el1 = el2; nd1 = nd2; sr1 = sr2;
        cur ^= 1;
        t += tstride;
    }
#undef LOADMETA
#undef STAGE
}

// ---------------------------------------------------------------------------
// Node GEMM  Y = f(A) @ W^T + bias, fused column sum/sumsq epilogue for BN
// stats. PRE=true applies gelu(a*scale+shift) on load.
// ---------------------------------------------------------------------------
template <bool PRE>
__global__ __launch_bounds__(256) void node_gemm(
    const float* __restrict__ A, const float* __restrict__ W,
    const float* __restrict__ bias, const float* __restrict__ scl,
    const float* __restrict__ shf, float* __restrict__ Y,
    float* __restrict__ csum, float* __restrict__ cssq, int Nn)
{
    __shared__ __align__(16) unsigned short alds[64 * 128];

    const int tid = threadIdx.x;
    const int w = tid >> 6, l = tid & 63, lg = l >> 4, lr = l & 15;
    const int er = tid >> 2, q = tid & 3;
    const int r0 = blockIdx.x * 64;

    bf16x8 bf[2][4];
    float bv[2];
#pragma unroll
    for (int n = 0; n < 2; ++n) {
        int row = w * 32 + n * 16 + lr;
        bv[n] = bias[row];
#pragma unroll
        for (int kk = 0; kk < 4; ++kk) {
            const float* p = W + row * H + kk * 32 + lg * 8;
            u16x8 t;
#pragma unroll
            for (int i = 0; i < 8; ++i) t[i] = f2bfu(p[i]);
            bf[n][kk] = __builtin_bit_cast(bf16x8, t);
        }
    }

    {
        int rr = r0 + er;
        int rc = rr < Nn ? rr : Nn - 1;
        const f32x4* pa = reinterpret_cast<const f32x4*>(A + (long)rc * H + q * 32);
        const int swz = (er & 7) << 3;
#pragma unroll
        for (int i = 0; i < 8; ++i) {
            f32x4 v = pa[i];
            if constexpr (PRE) {
                f32x4 sc = *reinterpret_cast<const f32x4*>(scl + q * 32 + i * 4);
                f32x4 sh = *reinterpret_cast<const f32x4*>(shf + q * 32 + i * 4);
#pragma unroll
                for (int c = 0; c < 4; ++c) v[c] = gelu_fast(v[c] * sc[c] + sh[c]);
            }
            u16x4 o;
            o[0] = f2bfu(v[0]);
            o[1] = f2bfu(v[1]);
            o[2] = f2bfu(v[2]);
            o[3] = f2bfu(v[3]);
            int col = q * 32 + i * 4;
            *reinterpret_cast<u16x4*>(&alds[er * 128 + (col ^ swz)]) = o;
        }
    }
    __syncthreads();

    float ps[2] = {0.f, 0.f}, ps2[2] = {0.f, 0.f};
#pragma unroll
    for (int m = 0; m < 4; ++m) {
        const int arow = m * 16 + lr;
        const int aswz = (arow & 7) << 3;
        bf16x8 af[4];
#pragma unroll
        for (int kk = 0; kk < 4; ++kk)
            af[kk] = __builtin_bit_cast(bf16x8,
                *reinterpret_cast<const u16x8*>(&alds[arow * 128 + ((kk * 32 + lg * 8) ^ aswz)]));
#pragma unroll
        for (int n = 0; n < 2; ++n) {
            f32x4 a4 = {0.f, 0.f, 0.f, 0.f};
#pragma unroll
            for (int kk = 0; kk < 4; ++kk)
                a4 = __builtin_amdgcn_mfma_f32_16x16x32_bf16(af[kk], bf[n][kk], a4, 0, 0, 0);
            const int j = w * 32 + n * 16 + lr;
#pragma unroll
            for (int r = 0; r < 4; ++r) {
                int rr = r0 + m * 16 + lg * 4 + r;
                if (rr < Nn) {
                    float z = a4[r] + bv[n];
                    Y[(long)rr * H + j] = z;
                    ps[n] += z;
                    ps2[n] += z * z;
                }
            }
        }
    }
#pragma unroll
    for (int n = 0; n < 2; ++n) {
        float s = ps[n];
        s += __shfl_xor(s, 16);
        s += __shfl_xor(s, 32);
        float s2 = ps2[n];
        s2 += __shfl_xor(s2, 16);
        s2 += __shfl_xor(s2, 32);
        if (lg == 0) {
            int j = w * 32 + n * 16 + lr;
            atomicAdd(&csum[j], s);
            atomicAdd(&cssq[j], s2);
        }
    }
}

__global__ void finalize_bn(const float* __restrict__ csum, const float* __restrict__ cssq,
                            const float* __restrict__ g, const float* __restrict__ be,
                            float* __restrict__ scl, float* __restrict__ shf, float invN)
{
    int j = threadIdx.x;
    float mu = csum[j] * invN;
    float var = fmaxf(cssq[j] * invN - mu * mu, 0.f);
    float s = g[j] * rsqrtf(var + EPS);
    scl[j] = s;
    shf[j] = be[j] - mu * s;
}

__global__ __launch_bounds__(256) void final_gelu(
    const float* __restrict__ Y2, const float* __restrict__ scl,
    const float* __restrict__ shf, float* __restrict__ out, long n4)
{
    long i = (long)blockIdx.x * blockDim.x + threadIdx.x;
    const long stride = (long)gridDim.x * blockDim.x;
    for (; i < n4; i += stride) {
        f32x4 v = reinterpret_cast<const f32x4*>(Y2)[i];
        int c4 = (int)(i & 31);
        f32x4 sc = reinterpret_cast<const f32x4*>(scl)[c4];
        f32x4 sh = reinterpret_cast<const f32x4*>(shf)[c4];
        f32x4 o;
#pragma unroll
        for (int c = 0; c < 4; ++c) o[c] = gelu_fast(v[c] * sc[c] + sh[c]);
        reinterpret_cast<f32x4*>(out)[i] = o;
    }
}

extern "C" void kernel_launch(void* const* d_in, const int* in_sizes, int n_in,
                              void* d_out, int out_size, void* d_ws, size_t ws_size,
                              hipStream_t stream) {
    const float* x     = (const float*)d_in[0];
    const float* ea    = (const float*)d_in[1];
    const float* bases = (const float*)d_in[2];
    const int*   src   = (const int*)d_in[3];
    const int*   dst   = (const int*)d_in[4];
    const float* W1    = (const float*)d_in[5];
    const float* b1    = (const float*)d_in[6];
    const float* W2    = (const float*)d_in[7];
    const float* b2    = (const float*)d_in[8];
    const float* g1    = (const float*)d_in[9];
    const float* be1   = (const float*)d_in[10];
    const float* W3    = (const float*)d_in[11];
    const float* b3    = (const float*)d_in[12];
    const float* g2    = (const float*)d_in[13];
    const float* be2   = (const float*)d_in[14];

    const int N = in_sizes[0] / H;
    const int E = in_sizes[1] / H;

    float* ws    = (float*)d_ws;
    float* aggr  = ws;                        // [N,H]; reused as y2
    float* y1    = aggr + (size_t)N * H;      // [N,H]
    float* stats = y1 + (size_t)N * H;        // 1024 floats
    float* sum1 = stats,        *ss1 = stats + 128;
    float* sum2 = stats + 256,  *ss2 = stats + 384;
    float* scl1 = stats + 512,  *shf1 = stats + 640;
    float* scl2 = stats + 768,  *shf2 = stats + 896;
    int* cnt  = (int*)(stats + 1024);         // [N] histogram
    int* cnt2 = cnt + N;                      // [N] scatter cursor (zeroed)
    int* perm = cnt2 + N;                     // [E]
    int* dsts = perm + E;                     // [E]
    int* offs = dsts + E;                     // [N+1]
    int* otmp = offs + N + 1;                 // [N] scan scratch
    int* bsum = otmp + N;                     // [256]
    int* boff = bsum + 256;                   // [256]
    unsigned short* xbf = (unsigned short*)(((uintptr_t)(boff + 256) + 4095) & ~(uintptr_t)4095); // [N,H] bf16

    // zero stats + cnt + cnt2, and aggr (atomic accumulation target)
    const int zn4 = (1024 + 2 * N + 3) / 4;
    zero_kernel<<<128, 256, 0, stream>>>((int*)stats, zn4);
    zero_kernel<<<1024, 256, 0, stream>>>((int*)aggr, N * H / 4);

    // x -> bf16
    convert_x<<<2048, 256, 0, stream>>>(x, xbf, (long)N * H / 8);

    // --- counting sort (perm + dsts + offs), multi-block scan ---
    const int nsb = (N + 255) / 256;
    hist_kernel<<<2048, 256, 0, stream>>>(dst, cnt, E);
    scan_p1<<<nsb, 256, 0, stream>>>(cnt, otmp, bsum, N);
    scan_p2<<<1, 256, 0, stream>>>(bsum, boff, nsb, offs, N, E);
    scan_p3<<<nsb, 256, 0, stream>>>(otmp, boff, offs, N);
    scatter_perm<<<2048, 256, 0, stream>>>(dst, offs, cnt2, perm, dsts, E);

    // --- persistent fused edge phase, double-buffered async prefetch ---
    edge_aggr<<<512, 256, 0, stream>>>(xbf, ea, bases, src, perm, dsts,
                                       W1, b1, aggr, E);

    // --- node pipeline ---
    const int nblk = (N + 63) / 64;
    node_gemm<false><<<nblk, 256, 0, stream>>>(aggr, W2, b2, nullptr, nullptr, y1, sum1, ss1, N);
    finalize_bn<<<1, 128, 0, stream>>>(sum1, ss1, g1, be1, scl1, shf1, 1.0f / (float)N);
    node_gemm<true><<<nblk, 256, 0, stream>>>(y1, W3, b3, scl1, shf1, aggr, sum2, ss2, N);
    finalize_bn<<<1, 128, 0, stream>>>(sum2, ss2, g2, be2, scl2, shf2, 1.0f / (float)N);

    long n4 = (long)N * H / 4;
    final_gelu<<<2048, 256, 0, stream>>>(aggr, scl2, shf2, (float*)d_out, n4);
}

// Round 15
// 397.860 us; speedup vs baseline: 1.2364x; 1.2364x over previous
//
#include <hip/hip_runtime.h>
#include <cmath>

#define H 128
#define EPS 1e-5f

typedef __attribute__((ext_vector_type(8))) __bf16 bf16x8;
typedef __attribute__((ext_vector_type(4))) float f32x4;
typedef __attribute__((ext_vector_type(2))) float f32x2;
typedef __attribute__((ext_vector_type(4))) unsigned short u16x4;
typedef __attribute__((ext_vector_type(8))) unsigned short u16x8;
typedef __attribute__((ext_vector_type(4))) int i32x4;

// Fast GELU (sigmoid form); verified R9: absmax unchanged vs erff.
__device__ __forceinline__ float gelu_fast(float x) {
    float t2 = -1.5957691216057308f * fmaf(0.044715f * x * x, x, x); // -2t
    return x * __builtin_amdgcn_rcpf(1.0f + __expf(t2));
}

__device__ __forceinline__ unsigned short f2bfu(float f) {
    __bf16 h = (__bf16)f;   // RNE fptrunc
    return __builtin_bit_cast(unsigned short, h);
}

__device__ __forceinline__ float bfu2f(unsigned short u) {
    return __builtin_bit_cast(float, (unsigned)u << 16);
}

// async global -> LDS, 16B per lane (lane i lands at ldsbase + i*16).
__device__ __forceinline__ void gld16(const void* g, void* l) {
    __builtin_amdgcn_global_load_lds(
        (__attribute__((address_space(1))) void*)(g),
        (__attribute__((address_space(3))) void*)(l), 16, 0, 0);
}

// ---------------------------------------------------------------------------
// Zero two scratch regions in ONE launch (in-graph hipMemsetAsync measured
// 195us for 324 KB in R7; kernel fills are ~5us).
// ---------------------------------------------------------------------------
__global__ __launch_bounds__(256) void zero2_kernel(int* __restrict__ a, int na4,
                                                    int* __restrict__ b, int nb4)
{
    int i = blockIdx.x * blockDim.x + threadIdx.x;
    const int stride = gridDim.x * blockDim.x;
    i32x4 z = {0, 0, 0, 0};
    const int tot = na4 + nb4;
    for (; i < tot; i += stride) {
        if (i < na4) reinterpret_cast<i32x4*>(a)[i] = z;
        else         reinterpret_cast<i32x4*>(b)[i - na4] = z;
    }
}

// ---------------------------------------------------------------------------
// x -> bf16 (halves x gather traffic; enables async x staging).
// ---------------------------------------------------------------------------
__global__ __launch_bounds__(256) void convert_x(const float* __restrict__ x,
                                                 unsigned short* __restrict__ xb,
                                                 long n8)
{
    long i = (long)blockIdx.x * blockDim.x + threadIdx.x;
    const long stride = (long)gridDim.x * blockDim.x;
    for (; i < n8; i += stride) {
        f32x4 a = *reinterpret_cast<const f32x4*>(x + i * 8);
        f32x4 b = *reinterpret_cast<const f32x4*>(x + i * 8 + 4);
        u16x8 o;
#pragma unroll
        for (int j = 0; j < 4; ++j) { o[j] = f2bfu(a[j]); o[j + 4] = f2bfu(b[j]); }
        *reinterpret_cast<u16x8*>(xb + i * 8) = o;
    }
}

// ---------------------------------------------------------------------------
// Counting sort of edges by dst -> perm, dsts, srcs, offs. Multi-block scan.
// ---------------------------------------------------------------------------
__global__ __launch_bounds__(256) void hist_kernel(const int* __restrict__ dst,
                                                   int* __restrict__ cnt, int E)
{
    int i = blockIdx.x * blockDim.x + threadIdx.x;
    const int stride = gridDim.x * blockDim.x;
    for (; i < E; i += stride) atomicAdd(&cnt[dst[i]], 1);
}

__global__ __launch_bounds__(256) void scan_p1(const int* __restrict__ cnt,
                                               int* __restrict__ otmp,
                                               int* __restrict__ bsum, int Nn)
{
    __shared__ int sh[256];
    const int t = threadIdx.x;
    const int idx = blockIdx.x * 256 + t;
    int v = idx < Nn ? cnt[idx] : 0;
    sh[t] = v;
    __syncthreads();
    for (int d = 1; d < 256; d <<= 1) {
        int u = (t >= d) ? sh[t - d] : 0;
        __syncthreads();
        sh[t] += u;
        __syncthreads();
    }
    if (idx < Nn) otmp[idx] = sh[t] - v;
    if (t == 255) bsum[blockIdx.x] = sh[t];
}

__global__ __launch_bounds__(256) void scan_p2(const int* __restrict__ bsum,
                                               int* __restrict__ boff, int nb,
                                               int* __restrict__ offs, int Nn, int E)
{
    __shared__ int sh[256];
    const int t = threadIdx.x;
    int v = t < nb ? bsum[t] : 0;
    sh[t] = v;
    __syncthreads();
    for (int d = 1; d < 256; d <<= 1) {
        int u = (t >= d) ? sh[t - d] : 0;
        __syncthreads();
        sh[t] += u;
        __syncthreads();
    }
    if (t < nb) boff[t] = sh[t] - v;
    if (t == 0) offs[Nn] = E;
}

__global__ __launch_bounds__(256) void scan_p3(const int* __restrict__ otmp,
                                               const int* __restrict__ boff,
                                               int* __restrict__ offs, int Nn)
{
    const int idx = blockIdx.x * 256 + threadIdx.x;
    if (idx < Nn) offs[idx] = otmp[idx] + boff[blockIdx.x];
}

__global__ __launch_bounds__(256) void scatter_perm(const int* __restrict__ dst,
                                                    const int* __restrict__ src,
                                                    const int* __restrict__ offs,
                                                    int* __restrict__ cur2,
                                                    int* __restrict__ perm,
                                                    int* __restrict__ dsts,
                                                    int* __restrict__ srcs, int E)
{
    int i = blockIdx.x * blockDim.x + threadIdx.x;
    const int stride = gridDim.x * blockDim.x;
    for (; i < E; i += stride) {
        int n = dst[i];
        int p = offs[n] + atomicAdd(&cur2[n], 1);
        perm[p] = i;
        dsts[p] = n;
        srcs[p] = src[i];
    }
}

// ---------------------------------------------------------------------------
// FULLY-FUSED edge phase over dst-sorted edges (R13 structure — best
// measured). ALL staging async (global_load_lds): ea f32, bases f32, x bf16.
// Swizzle via pre-XOR'd per-lane SOURCE chunk + XOR'd LDS read (rule #21).
// Swapped-operand MFMA (bias as C-init) -> gelu*bases -> Kogge-Stone
// segmented reduce across the 16-lane edge dim -> head-lane atomics.
// Metadata now 3 independent loads (perm/dsts/srcs) — no dependent chain.
// ---------------------------------------------------------------------------
__global__ __launch_bounds__(256, 2) void edge_aggr(
    const unsigned short* __restrict__ xbf, const float* __restrict__ ea,
    const float* __restrict__ bases,
    const int* __restrict__ perm, const int* __restrict__ dsts,
    const int* __restrict__ srcs,
    const float* __restrict__ W1, const float* __restrict__ b1,
    float* __restrict__ aggr, int E)
{
    __shared__ __align__(16) float ealds[64 * 128];            // 32 KB f32
    __shared__ __align__(16) float blds[64 * 128];             // 32 KB f32
    __shared__ __align__(16) unsigned short xlds[64 * 128];    // 16 KB bf16

    const int tid = threadIdx.x;
    const int w = tid >> 6, l = tid & 63, lg = l >> 4, lr = l & 15;

    // W1 A-fragments: rows w*32 + ni*16 + lr, k = kk*32 + lg*8 .. +8
    bf16x8 wf[2][4];
    f32x4 b1v[2];
#pragma unroll
    for (int ni = 0; ni < 2; ++ni) {
        int row = w * 32 + ni * 16 + lr;
#pragma unroll
        for (int kk = 0; kk < 4; ++kk) {
            const float* p = W1 + row * H + kk * 32 + lg * 8;
            u16x8 tt;
#pragma unroll
            for (int i = 0; i < 8; ++i) tt[i] = f2bfu(p[i]);
            wf[ni][kk] = __builtin_bit_cast(bf16x8, tt);
        }
        b1v[ni] = *reinterpret_cast<const f32x4*>(b1 + w * 32 + ni * 16 + lg * 4);
    }

    const int e0 = blockIdx.x * 64;
    // per-lane tile metadata: lane l <-> sorted position e0+l (3 parallel loads)
    int ic = e0 + l;
    ic = ic < E ? ic : E - 1;
    const int el_reg = perm[ic];
    const int nd_reg = dsts[ic];
    const int sr_reg = srcs[ic];

    // ---- async ea + bases staging (f32, source-swizzled) ----
#pragma unroll
    for (int j = 0; j < 8; ++j) {
        const int r = (w << 4) + (j << 1) + (l >> 5);   // row 0..63 (2/instr)
        const int e = __shfl(el_reg, r);
        const int cs = (l & 31) ^ (r & 7);              // 16B-chunk of 32, pre-swz
        const int rowbase = (((w << 4) + (j << 1)) << 7);  // floats
        gld16(ea + (long)e * H + cs * 4, &ealds[rowbase]);
        gld16(bases + (long)e * H + cs * 4, &blds[rowbase]);
    }

    // ---- async x staging (bf16, source-swizzled): 4 rows/instr ----
#pragma unroll
    for (int j = 0; j < 4; ++j) {
        const int r = (w << 4) + (j << 2) + (l >> 4);   // row 0..63 (4/instr)
        const int s = __shfl(sr_reg, r);
        const int cs = (l & 15) ^ (r & 7);              // 16B-chunk of 16, pre-swz
        const int rowbase = (((w << 4) + (j << 2)) << 7);  // ushorts
        gld16(xbf + (long)s * H + cs * 8, &xlds[rowbase]);
    }
    __syncthreads();   // drains vmcnt (global_load_lds) for the whole block

    // ---- compute + in-register segmented reduction + atomic epilogue ----
    const int col0base = w * 32 + lg * 4;
#pragma unroll
    for (int s = 0; s < 4; ++s) {
        const int arow = s * 16 + lr;
        const int fswz = arow & 7;            // 16B-chunk XOR

        // posE fragments: ea (f32 LDS) + x (bf16 LDS) -> bf16 pack
        bf16x8 af[4];
#pragma unroll
        for (int kk = 0; kk < 4; ++kk) {
            const int cc = kk * 8 + lg * 2;
            f32x4 elo = *reinterpret_cast<const f32x4*>(&ealds[arow * 128 + ((cc ^ fswz) << 2)]);
            f32x4 ehi = *reinterpret_cast<const f32x4*>(&ealds[arow * 128 + (((cc + 1) ^ fswz) << 2)]);
            u16x8 xv = *reinterpret_cast<const u16x8*>(&xlds[arow * 128 + (((kk * 4 + lg) ^ fswz) << 3)]);
            u16x8 o;
#pragma unroll
            for (int r = 0; r < 4; ++r) {
                o[r]     = f2bfu(elo[r] + bfu2f(xv[r]));
                o[r + 4] = f2bfu(ehi[r] + bfu2f(xv[r + 4]));
            }
            af[kk] = __builtin_bit_cast(bf16x8, o);
        }

        const int es = e0 + arow;
        const bool ok = es < E;
        const int nd = __shfl(nd_reg, arow);
        const int ndp = __shfl(nd_reg, arow - 1);   // arow==0 masked by lr==0
        const bool head = ok && (lr == 0 || nd != ndp);

#pragma unroll
        for (int ni = 0; ni < 2; ++ni) {
            f32x4 a4 = b1v[ni];   // bias as C-init
#pragma unroll
            for (int kk = 0; kk < 4; ++kk)
                a4 = __builtin_amdgcn_mfma_f32_16x16x32_bf16(wf[ni][kk], af[kk], a4, 0, 0, 0);

            const int col0 = col0base + ni * 16;
            const int bcc = col0 >> 2;
            f32x4 bq = *reinterpret_cast<const f32x4*>(&blds[arow * 128 + ((bcc ^ fswz) << 2)]);
            f32x4 v;
#pragma unroll
            for (int r = 0; r < 4; ++r)
                v[r] = ok ? gelu_fast(a4[r]) * bq[r] : 0.f;

            // Kogge-Stone segmented suffix-sum across lr (16-lane groups)
#pragma unroll
            for (int d = 1; d < 16; d <<= 1) {
                f32x4 vn;
#pragma unroll
                for (int r = 0; r < 4; ++r) vn[r] = __shfl_down(v[r], d);
                int ndn = __shfl_down(nd, d);
                bool take = (lr + d < 16) && (ndn == nd);
#pragma unroll
                for (int r = 0; r < 4; ++r) v[r] += take ? vn[r] : 0.f;
            }

            if (head) {
                float* dstp = aggr + (long)nd * H + col0;
#pragma unroll
                for (int r = 0; r < 4; ++r) atomicAdd(&dstp[r], v[r]);
            }
        }
    }
}

// ---------------------------------------------------------------------------
// Node GEMM  Y = f(A) @ W^T + bias, fused column sum/sumsq epilogue for BN
// stats. PRE=true computes BN1 scale/shift per-block from csum/cssq (folds
// the old finalize_bn kernel) and applies gelu(a*scale+shift) on load.
// ---------------------------------------------------------------------------
template <bool PRE>
__global__ __launch_bounds__(256) void node_gemm(
    const float* __restrict__ A, const float* __restrict__ W,
    const float* __restrict__ bias,
    const float* __restrict__ csumIn, const float* __restrict__ cssqIn,
    const float* __restrict__ gIn, const float* __restrict__ beIn, float invN,
    float* __restrict__ Y,
    float* __restrict__ csum, float* __restrict__ cssq, int Nn)
{
    __shared__ __align__(16) unsigned short alds[64 * 128];
    __shared__ float sclds[128], shlds[128];

    const int tid = threadIdx.x;
    const int w = tid >> 6, l = tid & 63, lg = l >> 4, lr = l & 15;
    const int er = tid >> 2, q = tid & 3;
    const int r0 = blockIdx.x * 64;

    if constexpr (PRE) {
        if (tid < 128) {
            float mu = csumIn[tid] * invN;
            float var = fmaxf(cssqIn[tid] * invN - mu * mu, 0.f);
            float sc = gIn[tid] * rsqrtf(var + EPS);
            sclds[tid] = sc;
            shlds[tid] = beIn[tid] - mu * sc;
        }
        __syncthreads();
    }

    bf16x8 bf[2][4];
    float bv[2];
#pragma unroll
    for (int n = 0; n < 2; ++n) {
        int row = w * 32 + n * 16 + lr;
        bv[n] = bias[row];
#pragma unroll
        for (int kk = 0; kk < 4; ++kk) {
            const float* p = W + row * H + kk * 32 + lg * 8;
            u16x8 t;
#pragma unroll
            for (int i = 0; i < 8; ++i) t[i] = f2bfu(p[i]);
            bf[n][kk] = __builtin_bit_cast(bf16x8, t);
        }
    }

    {
        int rr = r0 + er;
        int rc = rr < Nn ? rr : Nn - 1;
        const f32x4* pa = reinterpret_cast<const f32x4*>(A + (long)rc * H + q * 32);
        const int swz = (er & 7) << 3;
#pragma unroll
        for (int i = 0; i < 8; ++i) {
            f32x4 v = pa[i];
            if constexpr (PRE) {
                f32x4 sc = *reinterpret_cast<const f32x4*>(&sclds[q * 32 + i * 4]);
                f32x4 sh = *reinterpret_cast<const f32x4*>(&shlds[q * 32 + i * 4]);
#pragma unroll
                for (int c = 0; c < 4; ++c) v[c] = gelu_fast(v[c] * sc[c] + sh[c]);
            }
            u16x4 o;
            o[0] = f2bfu(v[0]);
            o[1] = f2bfu(v[1]);
            o[2] = f2bfu(v[2]);
            o[3] = f2bfu(v[3]);
            int col = q * 32 + i * 4;
            *reinterpret_cast<u16x4*>(&alds[er * 128 + (col ^ swz)]) = o;
        }
    }
    __syncthreads();

    float ps[2] = {0.f, 0.f}, ps2[2] = {0.f, 0.f};
#pragma unroll
    for (int m = 0; m < 4; ++m) {
        const int arow = m * 16 + lr;
        const int aswz = (arow & 7) << 3;
        bf16x8 af[4];
#pragma unroll
        for (int kk = 0; kk < 4; ++kk)
            af[kk] = __builtin_bit_cast(bf16x8,
                *reinterpret_cast<const u16x8*>(&alds[arow * 128 + ((kk * 32 + lg * 8) ^ aswz)]));
#pragma unroll
        for (int n = 0; n < 2; ++n) {
            f32x4 a4 = {0.f, 0.f, 0.f, 0.f};
#pragma unroll
            for (int kk = 0; kk < 4; ++kk)
                a4 = __builtin_amdgcn_mfma_f32_16x16x32_bf16(af[kk], bf[n][kk], a4, 0, 0, 0);
            const int j = w * 32 + n * 16 + lr;
#pragma unroll
            for (int r = 0; r < 4; ++r) {
                int rr = r0 + m * 16 + lg * 4 + r;
                if (rr < Nn) {
                    float z = a4[r] + bv[n];
                    Y[(long)rr * H + j] = z;
                    ps[n] += z;
                    ps2[n] += z * z;
                }
            }
        }
    }
#pragma unroll
    for (int n = 0; n < 2; ++n) {
        float s = ps[n];
        s += __shfl_xor(s, 16);
        s += __shfl_xor(s, 32);
        float s2 = ps2[n];
        s2 += __shfl_xor(s2, 16);
        s2 += __shfl_xor(s2, 32);
        if (lg == 0) {
            int j = w * 32 + n * 16 + lr;
            atomicAdd(&csum[j], s);
            atomicAdd(&cssq[j], s2);
        }
    }
}

// ---------------------------------------------------------------------------
// Final: out = gelu(y2 * scale2 + shift2). BN2 finalize folded in (per-block
// recompute from sum2/ss2 — 128 rsqrt, trivial).
// ---------------------------------------------------------------------------
__global__ __launch_bounds__(256) void final_gelu(
    const float* __restrict__ Y2,
    const float* __restrict__ csum, const float* __restrict__ cssq,
    const float* __restrict__ g, const float* __restrict__ be, float invN,
    float* __restrict__ out, long n4)
{
    __shared__ float sclds[128], shlds[128];
    if (threadIdx.x < 128) {
        int j = threadIdx.x;
        float mu = csum[j] * invN;
        float var = fmaxf(cssq[j] * invN - mu * mu, 0.f);
        float sc = g[j] * rsqrtf(var + EPS);
        sclds[j] = sc;
        shlds[j] = be[j] - mu * sc;
    }
    __syncthreads();

    long i = (long)blockIdx.x * blockDim.x + threadIdx.x;
    const long stride = (long)gridDim.x * blockDim.x;
    for (; i < n4; i += stride) {
        f32x4 v = reinterpret_cast<const f32x4*>(Y2)[i];
        int c4 = (int)(i & 31);
        f32x4 sc = *reinterpret_cast<const f32x4*>(&sclds[c4 * 4]);
        f32x4 sh = *reinterpret_cast<const f32x4*>(&shlds[c4 * 4]);
        f32x4 o;
#pragma unroll
        for (int c = 0; c < 4; ++c) o[c] = gelu_fast(v[c] * sc[c] + sh[c]);
        reinterpret_cast<f32x4*>(out)[i] = o;
    }
}

extern "C" void kernel_launch(void* const* d_in, const int* in_sizes, int n_in,
                              void* d_out, int out_size, void* d_ws, size_t ws_size,
                              hipStream_t stream) {
    const float* x     = (const float*)d_in[0];
    const float* ea    = (const float*)d_in[1];
    const float* bases = (const float*)d_in[2];
    const int*   src   = (const int*)d_in[3];
    const int*   dst   = (const int*)d_in[4];
    const float* W1    = (const float*)d_in[5];
    const float* b1    = (const float*)d_in[6];
    const float* W2    = (const float*)d_in[7];
    const float* b2    = (const float*)d_in[8];
    const float* g1    = (const float*)d_in[9];
    const float* be1   = (const float*)d_in[10];
    const float* W3    = (const float*)d_in[11];
    const float* b3    = (const float*)d_in[12];
    const float* g2    = (const float*)d_in[13];
    const float* be2   = (const float*)d_in[14];

    const int N = in_sizes[0] / H;
    const int E = in_sizes[1] / H;

    float* ws    = (float*)d_ws;
    float* aggr  = ws;                        // [N,H]; reused as y2
    float* y1    = aggr + (size_t)N * H;      // [N,H]
    float* stats = y1 + (size_t)N * H;        // 1024 floats
    float* sum1 = stats,        *ss1 = stats + 128;
    float* sum2 = stats + 256,  *ss2 = stats + 384;
    int* cnt  = (int*)(stats + 1024);         // [N] histogram
    int* cnt2 = cnt + N;                      // [N] scatter cursor (zeroed)
    int* perm = cnt2 + N;                     // [E]
    int* dsts = perm + E;                     // [E]
    int* srcs = dsts + E;                     // [E]
    int* offs = srcs + E;                     // [N+1]
    int* otmp = offs + N + 1;                 // [N] scan scratch
    int* bsum = otmp + N;                     // [256]
    int* boff = bsum + 256;                   // [256]
    unsigned short* xbf = (unsigned short*)(((uintptr_t)(boff + 256) + 4095) & ~(uintptr_t)4095); // [N,H] bf16

    const float invN = 1.0f / (float)N;

    // zero stats+cnt+cnt2 AND aggr in one launch
    const int zn4a = (1024 + 2 * N + 3) / 4;
    zero2_kernel<<<1024, 256, 0, stream>>>((int*)stats, zn4a, (int*)aggr, N * H / 4);

    // x -> bf16
    convert_x<<<2048, 256, 0, stream>>>(x, xbf, (long)N * H / 8);

    // --- counting sort (perm + dsts + srcs + offs), multi-block scan ---
    const int nsb = (N + 255) / 256;
    hist_kernel<<<2048, 256, 0, stream>>>(dst, cnt, E);
    scan_p1<<<nsb, 256, 0, stream>>>(cnt, otmp, bsum, N);
    scan_p2<<<1, 256, 0, stream>>>(bsum, boff, nsb, offs, N, E);
    scan_p3<<<nsb, 256, 0, stream>>>(otmp, boff, offs, N);
    scatter_perm<<<2048, 256, 0, stream>>>(dst, src, offs, cnt2, perm, dsts, srcs, E);

    // --- fully-fused edge phase (R13 structure, best measured) ---
    edge_aggr<<<(E + 63) / 64, 256, 0, stream>>>(xbf, ea, bases, perm, dsts, srcs,
                                                 W1, b1, aggr, E);

    // --- node pipeline (BN finalize folded into consumers) ---
    const int nblk = (N + 63) / 64;
    node_gemm<false><<<nblk, 256, 0, stream>>>(aggr, W2, b2,
                                               nullptr, nullptr, nullptr, nullptr, 0.f,
                                               y1, sum1, ss1, N);
    node_gemm<true><<<nblk, 256, 0, stream>>>(y1, W3, b3,
                                              sum1, ss1, g1, be1, invN,
                                              aggr, sum2, ss2, N);
    long n4 = (long)N * H / 4;
    final_gelu<<<2048, 256, 0, stream>>>(aggr, sum2, ss2, g2, be2, invN,
                                         (float*)d_out, n4);
}

// Round 16
// 395.621 us; speedup vs baseline: 1.2434x; 1.0057x over previous
//
#include <hip/hip_runtime.h>
#include <cmath>

#define H 128
#define EPS 1e-5f

typedef __attribute__((ext_vector_type(8))) __bf16 bf16x8;
typedef __attribute__((ext_vector_type(4))) float f32x4;
typedef __attribute__((ext_vector_type(2))) float f32x2;
typedef __attribute__((ext_vector_type(4))) unsigned short u16x4;
typedef __attribute__((ext_vector_type(8))) unsigned short u16x8;
typedef __attribute__((ext_vector_type(4))) int i32x4;

// Fast GELU (sigmoid form); verified R9: absmax unchanged vs erff.
__device__ __forceinline__ float gelu_fast(float x) {
    float t2 = -1.5957691216057308f * fmaf(0.044715f * x * x, x, x); // -2t
    return x * __builtin_amdgcn_rcpf(1.0f + __expf(t2));
}

__device__ __forceinline__ unsigned short f2bfu(float f) {
    __bf16 h = (__bf16)f;   // RNE fptrunc
    return __builtin_bit_cast(unsigned short, h);
}

__device__ __forceinline__ float bfu2f(unsigned short u) {
    return __builtin_bit_cast(float, (unsigned)u << 16);
}

// async global -> LDS, 16B per lane (lane i lands at ldsbase + i*16).
__device__ __forceinline__ void gld16(const void* g, void* l) {
    __builtin_amdgcn_global_load_lds(
        (__attribute__((address_space(1))) void*)(g),
        (__attribute__((address_space(3))) void*)(l), 16, 0, 0);
}

// ---------------------------------------------------------------------------
// Zero two scratch regions in ONE launch.
// ---------------------------------------------------------------------------
__global__ __launch_bounds__(256) void zero2_kernel(int* __restrict__ a, int na4,
                                                    int* __restrict__ b, int nb4)
{
    int i = blockIdx.x * blockDim.x + threadIdx.x;
    const int stride = gridDim.x * blockDim.x;
    i32x4 z = {0, 0, 0, 0};
    const int tot = na4 + nb4;
    for (; i < tot; i += stride) {
        if (i < na4) reinterpret_cast<i32x4*>(a)[i] = z;
        else         reinterpret_cast<i32x4*>(b)[i - na4] = z;
    }
}

// ---------------------------------------------------------------------------
// x -> bf16 (halves x gather traffic; enables async x staging).
// ---------------------------------------------------------------------------
__global__ __launch_bounds__(256) void convert_x(const float* __restrict__ x,
                                                 unsigned short* __restrict__ xb,
                                                 long n8)
{
    long i = (long)blockIdx.x * blockDim.x + threadIdx.x;
    const long stride = (long)gridDim.x * blockDim.x;
    for (; i < n8; i += stride) {
        f32x4 a = *reinterpret_cast<const f32x4*>(x + i * 8);
        f32x4 b = *reinterpret_cast<const f32x4*>(x + i * 8 + 4);
        u16x8 o;
#pragma unroll
        for (int j = 0; j < 4; ++j) { o[j] = f2bfu(a[j]); o[j + 4] = f2bfu(b[j]); }
        *reinterpret_cast<u16x8*>(xb + i * 8) = o;
    }
}

// ---------------------------------------------------------------------------
// Counting sort of edges by dst -> perm, dsts, srcs, offs. Multi-block scan.
// ---------------------------------------------------------------------------
__global__ __launch_bounds__(256) void hist_kernel(const int* __restrict__ dst,
                                                   int* __restrict__ cnt, int E)
{
    int i = blockIdx.x * blockDim.x + threadIdx.x;
    const int stride = gridDim.x * blockDim.x;
    for (; i < E; i += stride) atomicAdd(&cnt[dst[i]], 1);
}

__global__ __launch_bounds__(256) void scan_p1(const int* __restrict__ cnt,
                                               int* __restrict__ otmp,
                                               int* __restrict__ bsum, int Nn)
{
    __shared__ int sh[256];
    const int t = threadIdx.x;
    const int idx = blockIdx.x * 256 + t;
    int v = idx < Nn ? cnt[idx] : 0;
    sh[t] = v;
    __syncthreads();
    for (int d = 1; d < 256; d <<= 1) {
        int u = (t >= d) ? sh[t - d] : 0;
        __syncthreads();
        sh[t] += u;
        __syncthreads();
    }
    if (idx < Nn) otmp[idx] = sh[t] - v;
    if (t == 255) bsum[blockIdx.x] = sh[t];
}

__global__ __launch_bounds__(256) void scan_p2(const int* __restrict__ bsum,
                                               int* __restrict__ boff, int nb,
                                               int* __restrict__ offs, int Nn, int E)
{
    __shared__ int sh[256];
    const int t = threadIdx.x;
    int v = t < nb ? bsum[t] : 0;
    sh[t] = v;
    __syncthreads();
    for (int d = 1; d < 256; d <<= 1) {
        int u = (t >= d) ? sh[t - d] : 0;
        __syncthreads();
        sh[t] += u;
        __syncthreads();
    }
    if (t < nb) boff[t] = sh[t] - v;
    if (t == 0) offs[Nn] = E;
}

__global__ __launch_bounds__(256) void scan_p3(const int* __restrict__ otmp,
                                               const int* __restrict__ boff,
                                               int* __restrict__ offs, int Nn)
{
    const int idx = blockIdx.x * 256 + threadIdx.x;
    if (idx < Nn) offs[idx] = otmp[idx] + boff[blockIdx.x];
}

__global__ __launch_bounds__(256) void scatter_perm(const int* __restrict__ dst,
                                                    const int* __restrict__ src,
                                                    const int* __restrict__ offs,
                                                    int* __restrict__ cur2,
                                                    int* __restrict__ perm,
                                                    int* __restrict__ dsts,
                                                    int* __restrict__ srcs, int E)
{
    int i = blockIdx.x * blockDim.x + threadIdx.x;
    const int stride = gridDim.x * blockDim.x;
    for (; i < E; i += stride) {
        int n = dst[i];
        int p = offs[n] + atomicAdd(&cur2[n], 1);
        perm[p] = i;
        dsts[p] = n;
        srcs[p] = src[i];
    }
}

// ---------------------------------------------------------------------------
// FULLY-FUSED edge phase over dst-sorted edges — R15 dataflow at TILE=32:
// LDS 40 KB -> 4 blocks/CU (vs 2 at tile 64), doubling waves/SIMD on the
// identical latency-bound pipeline. ALL staging async (global_load_lds):
// ea f32, bases f32, x bf16; swizzle via pre-XOR'd source chunk (rule #21).
// Swapped-operand MFMA (bias as C-init) -> gelu*bases -> Kogge-Stone
// segmented reduce across the 16-lane edge dim -> head-lane atomics.
// ---------------------------------------------------------------------------
__global__ __launch_bounds__(256, 4) void edge_aggr(
    const unsigned short* __restrict__ xbf, const float* __restrict__ ea,
    const float* __restrict__ bases,
    const int* __restrict__ perm, const int* __restrict__ dsts,
    const int* __restrict__ srcs,
    const float* __restrict__ W1, const float* __restrict__ b1,
    float* __restrict__ aggr, int E)
{
    __shared__ __align__(16) float ealds[32 * 128];            // 16 KB f32
    __shared__ __align__(16) float blds[32 * 128];             // 16 KB f32
    __shared__ __align__(16) unsigned short xlds[32 * 128];    // 8 KB bf16

    const int tid = threadIdx.x;
    const int w = tid >> 6, l = tid & 63, lg = l >> 4, lr = l & 15;

    // W1 A-fragments: rows w*32 + ni*16 + lr, k = kk*32 + lg*8 .. +8
    bf16x8 wf[2][4];
    f32x4 b1v[2];
#pragma unroll
    for (int ni = 0; ni < 2; ++ni) {
        int row = w * 32 + ni * 16 + lr;
#pragma unroll
        for (int kk = 0; kk < 4; ++kk) {
            const float* p = W1 + row * H + kk * 32 + lg * 8;
            u16x8 tt;
#pragma unroll
            for (int i = 0; i < 8; ++i) tt[i] = f2bfu(p[i]);
            wf[ni][kk] = __builtin_bit_cast(bf16x8, tt);
        }
        b1v[ni] = *reinterpret_cast<const f32x4*>(b1 + w * 32 + ni * 16 + lg * 4);
    }

    const int e0 = blockIdx.x * 32;
    // per-lane tile metadata: lane (l&31) <-> sorted position e0+(l&31)
    int ic = e0 + (l & 31);
    ic = ic < E ? ic : E - 1;
    const int el_reg = perm[ic];
    const int nd_reg = dsts[ic];
    const int sr_reg = srcs[ic];

    // ---- async ea + bases staging (f32, source-swizzled): 2 rows/instr ----
#pragma unroll
    for (int j = 0; j < 4; ++j) {
        const int r = (w << 3) + (j << 1) + (l >> 5);   // row 0..31
        const int e = __shfl(el_reg, r);
        const int cs = (l & 31) ^ (r & 7);              // 16B-chunk of 32, pre-swz
        const int rowbase = (((w << 3) + (j << 1)) << 7);  // floats
        gld16(ea + (long)e * H + cs * 4, &ealds[rowbase]);
        gld16(bases + (long)e * H + cs * 4, &blds[rowbase]);
    }

    // ---- async x staging (bf16, source-swizzled): 4 rows/instr ----
#pragma unroll
    for (int j = 0; j < 2; ++j) {
        const int r = (w << 3) + (j << 2) + (l >> 4);   // row 0..31
        const int s = __shfl(sr_reg, r);
        const int cs = (l & 15) ^ (r & 7);              // 16B-chunk of 16, pre-swz
        const int rowbase = (((w << 3) + (j << 2)) << 7);  // ushorts
        gld16(xbf + (long)s * H + cs * 8, &xlds[rowbase]);
    }
    __syncthreads();   // drains vmcnt (global_load_lds) for the whole block

    // ---- compute + in-register segmented reduction + atomic epilogue ----
    const int col0base = w * 32 + lg * 4;
#pragma unroll
    for (int s = 0; s < 2; ++s) {
        const int arow = s * 16 + lr;
        const int fswz = arow & 7;            // 16B-chunk XOR

        // posE fragments: ea (f32 LDS) + x (bf16 LDS) -> bf16 pack
        bf16x8 af[4];
#pragma unroll
        for (int kk = 0; kk < 4; ++kk) {
            const int cc = kk * 8 + lg * 2;
            f32x4 elo = *reinterpret_cast<const f32x4*>(&ealds[arow * 128 + ((cc ^ fswz) << 2)]);
            f32x4 ehi = *reinterpret_cast<const f32x4*>(&ealds[arow * 128 + (((cc + 1) ^ fswz) << 2)]);
            u16x8 xv = *reinterpret_cast<const u16x8*>(&xlds[arow * 128 + (((kk * 4 + lg) ^ fswz) << 3)]);
            u16x8 o;
#pragma unroll
            for (int r = 0; r < 4; ++r) {
                o[r]     = f2bfu(elo[r] + bfu2f(xv[r]));
                o[r + 4] = f2bfu(ehi[r] + bfu2f(xv[r + 4]));
            }
            af[kk] = __builtin_bit_cast(bf16x8, o);
        }

        const int es = e0 + arow;
        const bool ok = es < E;
        const int nd = __shfl(nd_reg, arow);
        const int ndp = __shfl(nd_reg, arow - 1);   // arow==0 masked by lr==0
        const bool head = ok && (lr == 0 || nd != ndp);

#pragma unroll
        for (int ni = 0; ni < 2; ++ni) {
            f32x4 a4 = b1v[ni];   // bias as C-init
#pragma unroll
            for (int kk = 0; kk < 4; ++kk)
                a4 = __builtin_amdgcn_mfma_f32_16x16x32_bf16(wf[ni][kk], af[kk], a4, 0, 0, 0);

            const int col0 = col0base + ni * 16;
            const int bcc = col0 >> 2;
            f32x4 bq = *reinterpret_cast<const f32x4*>(&blds[arow * 128 + ((bcc ^ fswz) << 2)]);
            f32x4 v;
#pragma unroll
            for (int r = 0; r < 4; ++r)
                v[r] = ok ? gelu_fast(a4[r]) * bq[r] : 0.f;

            // Kogge-Stone segmented suffix-sum across lr (16-lane groups)
#pragma unroll
            for (int d = 1; d < 16; d <<= 1) {
                f32x4 vn;
#pragma unroll
                for (int r = 0; r < 4; ++r) vn[r] = __shfl_down(v[r], d);
                int ndn = __shfl_down(nd, d);
                bool take = (lr + d < 16) && (ndn == nd);
#pragma unroll
                for (int r = 0; r < 4; ++r) v[r] += take ? vn[r] : 0.f;
            }

            if (head) {
                float* dstp = aggr + (long)nd * H + col0;
#pragma unroll
                for (int r = 0; r < 4; ++r) atomicAdd(&dstp[r], v[r]);
            }
        }
    }
}

// ---------------------------------------------------------------------------
// Node GEMM  Y = f(A) @ W^T + bias, fused column sum/sumsq epilogue for BN
// stats. PRE=true computes BN1 scale/shift per-block from csum/cssq (folds
// the old finalize_bn kernel) and applies gelu(a*scale+shift) on load.
// ---------------------------------------------------------------------------
template <bool PRE>
__global__ __launch_bounds__(256) void node_gemm(
    const float* __restrict__ A, const float* __restrict__ W,
    const float* __restrict__ bias,
    const float* __restrict__ csumIn, const float* __restrict__ cssqIn,
    const float* __restrict__ gIn, const float* __restrict__ beIn, float invN,
    float* __restrict__ Y,
    float* __restrict__ csum, float* __restrict__ cssq, int Nn)
{
    __shared__ __align__(16) unsigned short alds[64 * 128];
    __shared__ float sclds[128], shlds[128];

    const int tid = threadIdx.x;
    const int w = tid >> 6, l = tid & 63, lg = l >> 4, lr = l & 15;
    const int er = tid >> 2, q = tid & 3;
    const int r0 = blockIdx.x * 64;

    if constexpr (PRE) {
        if (tid < 128) {
            float mu = csumIn[tid] * invN;
            float var = fmaxf(cssqIn[tid] * invN - mu * mu, 0.f);
            float sc = gIn[tid] * rsqrtf(var + EPS);
            sclds[tid] = sc;
            shlds[tid] = beIn[tid] - mu * sc;
        }
        __syncthreads();
    }

    bf16x8 bf[2][4];
    float bv[2];
#pragma unroll
    for (int n = 0; n < 2; ++n) {
        int row = w * 32 + n * 16 + lr;
        bv[n] = bias[row];
#pragma unroll
        for (int kk = 0; kk < 4; ++kk) {
            const float* p = W + row * H + kk * 32 + lg * 8;
            u16x8 t;
#pragma unroll
            for (int i = 0; i < 8; ++i) t[i] = f2bfu(p[i]);
            bf[n][kk] = __builtin_bit_cast(bf16x8, t);
        }
    }

    {
        int rr = r0 + er;
        int rc = rr < Nn ? rr : Nn - 1;
        const f32x4* pa = reinterpret_cast<const f32x4*>(A + (long)rc * H + q * 32);
        const int swz = (er & 7) << 3;
#pragma unroll
        for (int i = 0; i < 8; ++i) {
            f32x4 v = pa[i];
            if constexpr (PRE) {
                f32x4 sc = *reinterpret_cast<const f32x4*>(&sclds[q * 32 + i * 4]);
                f32x4 sh = *reinterpret_cast<const f32x4*>(&shlds[q * 32 + i * 4]);
#pragma unroll
                for (int c = 0; c < 4; ++c) v[c] = gelu_fast(v[c] * sc[c] + sh[c]);
            }
            u16x4 o;
            o[0] = f2bfu(v[0]);
            o[1] = f2bfu(v[1]);
            o[2] = f2bfu(v[2]);
            o[3] = f2bfu(v[3]);
            int col = q * 32 + i * 4;
            *reinterpret_cast<u16x4*>(&alds[er * 128 + (col ^ swz)]) = o;
        }
    }
    __syncthreads();

    float ps[2] = {0.f, 0.f}, ps2[2] = {0.f, 0.f};
#pragma unroll
    for (int m = 0; m < 4; ++m) {
        const int arow = m * 16 + lr;
        const int aswz = (arow & 7) << 3;
        bf16x8 af[4];
#pragma unroll
        for (int kk = 0; kk < 4; ++kk)
            af[kk] = __builtin_bit_cast(bf16x8,
                *reinterpret_cast<const u16x8*>(&alds[arow * 128 + ((kk * 32 + lg * 8) ^ aswz)]));
#pragma unroll
        for (int n = 0; n < 2; ++n) {
            f32x4 a4 = {0.f, 0.f, 0.f, 0.f};
#pragma unroll
            for (int kk = 0; kk < 4; ++kk)
                a4 = __builtin_amdgcn_mfma_f32_16x16x32_bf16(af[kk], bf[n][kk], a4, 0, 0, 0);
            const int j = w * 32 + n * 16 + lr;
#pragma unroll
            for (int r = 0; r < 4; ++r) {
                int rr = r0 + m * 16 + lg * 4 + r;
                if (rr < Nn) {
                    float z = a4[r] + bv[n];
                    Y[(long)rr * H + j] = z;
                    ps[n] += z;
                    ps2[n] += z * z;
                }
            }
        }
    }
#pragma unroll
    for (int n = 0; n < 2; ++n) {
        float s = ps[n];
        s += __shfl_xor(s, 16);
        s += __shfl_xor(s, 32);
        float s2 = ps2[n];
        s2 += __shfl_xor(s2, 16);
        s2 += __shfl_xor(s2, 32);
        if (lg == 0) {
            int j = w * 32 + n * 16 + lr;
            atomicAdd(&csum[j], s);
            atomicAdd(&cssq[j], s2);
        }
    }
}

// ---------------------------------------------------------------------------
// Final: out = gelu(y2 * scale2 + shift2). BN2 finalize folded in.
// ---------------------------------------------------------------------------
__global__ __launch_bounds__(256) void final_gelu(
    const float* __restrict__ Y2,
    const float* __restrict__ csum, const float* __restrict__ cssq,
    const float* __restrict__ g, const float* __restrict__ be, float invN,
    float* __restrict__ out, long n4)
{
    __shared__ float sclds[128], shlds[128];
    if (threadIdx.x < 128) {
        int j = threadIdx.x;
        float mu = csum[j] * invN;
        float var = fmaxf(cssq[j] * invN - mu * mu, 0.f);
        float sc = g[j] * rsqrtf(var + EPS);
        sclds[j] = sc;
        shlds[j] = be[j] - mu * sc;
    }
    __syncthreads();

    long i = (long)blockIdx.x * blockDim.x + threadIdx.x;
    const long stride = (long)gridDim.x * blockDim.x;
    for (; i < n4; i += stride) {
        f32x4 v = reinterpret_cast<const f32x4*>(Y2)[i];
        int c4 = (int)(i & 31);
        f32x4 sc = *reinterpret_cast<const f32x4*>(&sclds[c4 * 4]);
        f32x4 sh = *reinterpret_cast<const f32x4*>(&shlds[c4 * 4]);
        f32x4 o;
#pragma unroll
        for (int c = 0; c < 4; ++c) o[c] = gelu_fast(v[c] * sc[c] + sh[c]);
        reinterpret_cast<f32x4*>(out)[i] = o;
    }
}

extern "C" void kernel_launch(void* const* d_in, const int* in_sizes, int n_in,
                              void* d_out, int out_size, void* d_ws, size_t ws_size,
                              hipStream_t stream) {
    const float* x     = (const float*)d_in[0];
    const float* ea    = (const float*)d_in[1];
    const float* bases = (const float*)d_in[2];
    const int*   src   = (const int*)d_in[3];
    const int*   dst   = (const int*)d_in[4];
    const float* W1    = (const float*)d_in[5];
    const float* b1    = (const float*)d_in[6];
    const float* W2    = (const float*)d_in[7];
    const float* b2    = (const float*)d_in[8];
    const float* g1    = (const float*)d_in[9];
    const float* be1   = (const float*)d_in[10];
    const float* W3    = (const float*)d_in[11];
    const float* b3    = (const float*)d_in[12];
    const float* g2    = (const float*)d_in[13];
    const float* be2   = (const float*)d_in[14];

    const int N = in_sizes[0] / H;
    const int E = in_sizes[1] / H;

    float* ws    = (float*)d_ws;
    float* aggr  = ws;                        // [N,H]; reused as y2
    float* y1    = aggr + (size_t)N * H;      // [N,H]
    float* stats = y1 + (size_t)N * H;        // 1024 floats
    float* sum1 = stats,        *ss1 = stats + 128;
    float* sum2 = stats + 256,  *ss2 = stats + 384;
    int* cnt  = (int*)(stats + 1024);         // [N] histogram
    int* cnt2 = cnt + N;                      // [N] scatter cursor (zeroed)
    int* perm = cnt2 + N;                     // [E]
    int* dsts = perm + E;                     // [E]
    int* srcs = dsts + E;                     // [E]
    int* offs = srcs + E;                     // [N+1]
    int* otmp = offs + N + 1;                 // [N] scan scratch
    int* bsum = otmp + N;                     // [256]
    int* boff = bsum + 256;                   // [256]
    unsigned short* xbf = (unsigned short*)(((uintptr_t)(boff + 256) + 4095) & ~(uintptr_t)4095); // [N,H] bf16

    const float invN = 1.0f / (float)N;

    // zero stats+cnt+cnt2 AND aggr in one launch
    const int zn4a = (1024 + 2 * N + 3) / 4;
    zero2_kernel<<<1024, 256, 0, stream>>>((int*)stats, zn4a, (int*)aggr, N * H / 4);

    // x -> bf16
    convert_x<<<2048, 256, 0, stream>>>(x, xbf, (long)N * H / 8);

    // --- counting sort (perm + dsts + srcs + offs), multi-block scan ---
    const int nsb = (N + 255) / 256;
    hist_kernel<<<2048, 256, 0, stream>>>(dst, cnt, E);
    scan_p1<<<nsb, 256, 0, stream>>>(cnt, otmp, bsum, N);
    scan_p2<<<1, 256, 0, stream>>>(bsum, boff, nsb, offs, N, E);
    scan_p3<<<nsb, 256, 0, stream>>>(otmp, boff, offs, N);
    scatter_perm<<<2048, 256, 0, stream>>>(dst, src, offs, cnt2, perm, dsts, srcs, E);

    // --- fully-fused edge phase, TILE=32 (40 KB LDS -> 4 blocks/CU) ---
    edge_aggr<<<(E + 31) / 32, 256, 0, stream>>>(xbf, ea, bases, perm, dsts, srcs,
                                                 W1, b1, aggr, E);

    // --- node pipeline (BN finalize folded into consumers) ---
    const int nblk = (N + 63) / 64;
    node_gemm<false><<<nblk, 256, 0, stream>>>(aggr, W2, b2,
                                               nullptr, nullptr, nullptr, nullptr, 0.f,
                                               y1, sum1, ss1, N);
    node_gemm<true><<<nblk, 256, 0, stream>>>(y1, W3, b3,
                                              sum1, ss1, g1, be1, invN,
                                              aggr, sum2, ss2, N);
    long n4 = (long)N * H / 4;
    final_gelu<<<2048, 256, 0, stream>>>(aggr, sum2, ss2, g2, be2, invN,
                                         (float*)d_out, n4);
}